// Round 1
// baseline (963.890 us; speedup 1.0000x reference)
//
#include <hip/hip_runtime.h>
#include <math.h>
#include <float.h>

// Problem constants (HierNet_55705725829422)
#define NN 50000      // nodes
#define EE 800000     // edges
#define CAP 64        // max in-degree capacity for CSR buckets (Poisson(16) -> P(>=64) ~ 1e-19)

__device__ __constant__ float kAVG_LOG = 2.8332133440562162f; // log(17)

__global__ __launch_bounds__(256) void zero_kernel(int* p, int n) {
    int i = blockIdx.x * 256 + threadIdx.x;
    if (i < n) p[i] = 0;
}

__global__ __launch_bounds__(256) void build_csr(const int* __restrict__ ei, const float* __restrict__ ea,
                                                 int* __restrict__ cnt, int* __restrict__ csr_src,
                                                 float2* __restrict__ csr_ea) {
    int e = blockIdx.x * 256 + threadIdx.x;
    if (e >= EE) return;
    int s = ei[e];
    int d = ei[EE + e];
    int p = atomicAdd(&cnt[d], 1);
    if (p < CAP) {
        csr_src[d * CAP + p] = s;
        csr_ea[d * CAP + p] = make_float2(ea[2 * e], ea[2 * e + 1]);
    }
}

// U[c*TF + f] = sum_g We[c,g]*Wpre[t,2F+g,o]  (f=t*F+o); Wab repack; bias_ab = be@Wpre_enc + bpre on A cols
template <int F>
__global__ __launch_bounds__(256) void prep_weights(const float* __restrict__ We, const float* __restrict__ be,
                                                    const float* __restrict__ Wpre, const float* __restrict__ bpre,
                                                    float* __restrict__ U, float* __restrict__ Wab,
                                                    float* __restrict__ bias_ab) {
    const int TF = 2 * F;
    int tid = threadIdx.x;
    for (int idx = tid; idx < 2 * TF; idx += 256) {
        int c = idx / TF, f = idx % TF;
        int t = f / F, o = f % F;
        float s = 0.f;
        for (int g = 0; g < F; ++g)
            s += We[c * F + g] * Wpre[((size_t)t * 3 * F + 2 * F + g) * F + o];
        U[idx] = s;
    }
    for (int idx = tid; idx < F * 2 * TF; idx += 256) {
        int g = idx / (2 * TF), cc = idx % (2 * TF);
        int t, o, row;
        if (cc < TF) { t = cc / F; o = cc % F; row = g; }
        else { int c2 = cc - TF; t = c2 / F; o = c2 % F; row = F + g; }
        Wab[idx] = Wpre[((size_t)t * 3 * F + row) * F + o];
    }
    for (int cc = tid; cc < 2 * TF; cc += 256) {
        float v = 0.f;
        if (cc < TF) {
            int t = cc / F, o = cc % F;
            float s = 0.f;
            for (int g = 0; g < F; ++g)
                s += be[g] * Wpre[((size_t)t * 3 * F + 2 * F + g) * F + o];
            v = s + bpre[t * F + o];
        }
        bias_ab[cc] = v;
    }
}

// C[M x Ncols] = A[M x K] @ B[K x Ncols] + bias (opt relu). grid(ceil(M/64), Ncols/64)
template <bool RELU>
__global__ __launch_bounds__(256) void gemm_tiled(const float* __restrict__ A, const float* __restrict__ B,
                                                  const float* __restrict__ bias, float* __restrict__ C,
                                                  int M, int K, int Ncols) {
    __shared__ float As[64][65];
    __shared__ float Bs[64][64];
    int m0 = blockIdx.x * 64, c0 = blockIdx.y * 64;
    int tid = threadIdx.x;
    int tx = tid % 16, ty = tid / 16;
    float acc[4][4] = {};
    for (int k0 = 0; k0 < K; k0 += 64) {
        for (int idx = tid; idx < 64 * 64; idx += 256) {
            int k = idx % 64, m = idx / 64;
            int gm = m0 + m, gk = k0 + k;
            As[m][k] = (gm < M && gk < K) ? A[(size_t)gm * K + gk] : 0.f;
        }
        for (int idx = tid; idx < 64 * 64; idx += 256) {
            int c = idx % 64, k = idx / 64;
            int gk = k0 + k;
            Bs[k][c] = (gk < K) ? B[(size_t)gk * Ncols + c0 + c] : 0.f;
        }
        __syncthreads();
#pragma unroll 8
        for (int k = 0; k < 64; ++k) {
            float a_[4], b_[4];
#pragma unroll
            for (int i = 0; i < 4; ++i) a_[i] = As[ty * 4 + i][k];
#pragma unroll
            for (int j = 0; j < 4; ++j) b_[j] = Bs[k][tx * 4 + j];
#pragma unroll
            for (int i = 0; i < 4; ++i)
#pragma unroll
                for (int j = 0; j < 4; ++j) acc[i][j] = fmaf(a_[i], b_[j], acc[i][j]);
        }
        __syncthreads();
    }
#pragma unroll
    for (int i = 0; i < 4; ++i) {
        int gm = m0 + ty * 4 + i;
        if (gm >= M) continue;
#pragma unroll
        for (int j = 0; j < 4; ++j) {
            int c = c0 + tx * 4 + j;
            float v = acc[i][j] + (bias ? bias[c] : 0.f);
            if (RELU) v = fmaxf(v, 0.f);
            C[(size_t)gm * Ncols + c] = v;
        }
    }
}

// one wave per node: m = (A[n]+u) + B[src] + ea.x*U0 + ea.y*U1; mean/min/max/std
template <int F>
__global__ __launch_bounds__(256) void aggregate(const float* __restrict__ AB, const int* __restrict__ cnt,
                                                 const int* __restrict__ csr_src, const float2* __restrict__ csr_ea,
                                                 const float* __restrict__ U, float* __restrict__ agg,
                                                 float2* __restrict__ sc) {
    const int TF = 2 * F;
    const int FPL = TF / 64;
    int wave = threadIdx.x >> 6, lane = threadIdx.x & 63;
    int n = blockIdx.x * 4 + wave;
    if (n >= NN) return;

    float base[FPL], u0[FPL], u1[FPL], sum[FPL], sq[FPL], mn[FPL], mx[FPL];
#pragma unroll
    for (int r = 0; r < FPL; ++r) {
        int f = lane + 64 * r;
        base[r] = AB[(size_t)n * (2 * TF) + f];
        u0[r] = U[f];
        u1[r] = U[TF + f];
        sum[r] = 0.f; sq[r] = 0.f; mn[r] = FLT_MAX; mx[r] = -FLT_MAX;
    }
    int deg = cnt[n];
    int ec = deg < CAP ? deg : CAP;
    const int ebase = n * CAP;
    for (int e = 0; e < ec; ++e) {
        int s = csr_src[ebase + e];
        float2 ea = csr_ea[ebase + e];
        const float* Brow = AB + (size_t)s * (2 * TF) + TF;
#pragma unroll
        for (int r = 0; r < FPL; ++r) {
            int f = lane + 64 * r;
            float m = base[r] + Brow[f] + ea.x * u0[r] + ea.y * u1[r];
            sum[r] += m;
            sq[r] = fmaf(m, m, sq[r]);
            mn[r] = fminf(mn[r], m);
            mx[r] = fmaxf(mx[r], m);
        }
    }
    float d = (float)(deg > 1 ? deg : 1);
    float inv_d = 1.f / d;
#pragma unroll
    for (int r = 0; r < FPL; ++r) {
        int f = lane + 64 * r;
        float mean = sum[r] * inv_d;
        float msq = sq[r] * inv_d;
        float var = msq - mean * mean;
        float stdv = sqrtf(fmaxf(var, 0.f) + 1e-5f);
        float vmn = deg > 0 ? mn[r] : 0.f;
        float vmx = deg > 0 ? mx[r] : 0.f;
        int t = f / F, o = f % F;
        size_t rowb = (size_t)n * (4 * TF) + (size_t)t * (4 * F);
        agg[rowb + o] = mean;
        agg[rowb + F + o] = vmn;
        agg[rowb + 2 * F + o] = vmx;
        agg[rowb + 3 * F + o] = stdv;
    }
    if (lane == 0) {
        float logd = logf(d + 1.f);
        sc[n] = make_float2(logd / kAVG_LOG, kAVG_LOG / logd);
    }
}

// o[n, t*32+fo] = [x | agg | s1*agg | s2*agg](n,t) @ Wpost[t] + bpost[t]; grid(ceil(N/64), 2)
template <int F>
__global__ __launch_bounds__(256) void post_gemm(const float* __restrict__ xin, const float* __restrict__ agg,
                                                 const float2* __restrict__ sc, const float* __restrict__ Wpost,
                                                 const float* __restrict__ bpost, float* __restrict__ obuf) {
    const int K = 13 * F;
    const int AGG = 4 * F;
    const int TSTR = 8 * F;
    __shared__ float As[64][65];
    __shared__ float Bs[64][32];
    __shared__ float2 scs[64];
    int m0 = blockIdx.x * 64;
    int t = blockIdx.y;
    int tid = threadIdx.x;
    if (tid < 64) {
        int gm = m0 + tid;
        scs[tid] = (gm < NN) ? sc[gm] : make_float2(1.f, 1.f);
    }
    __syncthreads();
    int tx = tid % 8, ty = tid / 8;
    float acc[2][4] = {};
    for (int k0 = 0; k0 < K; k0 += 64) {
        for (int idx = tid; idx < 64 * 64; idx += 256) {
            int k = idx % 64, m = idx / 64;
            int gm = m0 + m, gk = k0 + k;
            float v = 0.f;
            if (gm < NN && gk < K) {
                if (gk < F) {
                    v = xin[(size_t)gm * F + gk];
                } else {
                    int j = gk - F;
                    int b = j / AGG;
                    int a = j - b * AGG;
                    float s = (b == 0) ? 1.f : ((b == 1) ? scs[m].x : scs[m].y);
                    v = agg[(size_t)gm * TSTR + (size_t)t * AGG + a] * s;
                }
            }
            As[m][k] = v;
        }
        for (int idx = tid; idx < 64 * 32; idx += 256) {
            int c = idx % 32, k = idx / 32;
            int gk = k0 + k;
            Bs[k][c] = (gk < K) ? Wpost[((size_t)t * K + gk) * 32 + c] : 0.f;
        }
        __syncthreads();
#pragma unroll 8
        for (int k = 0; k < 64; ++k) {
            float a_[2], b_[4];
#pragma unroll
            for (int i = 0; i < 2; ++i) a_[i] = As[ty * 2 + i][k];
#pragma unroll
            for (int j = 0; j < 4; ++j) b_[j] = Bs[k][tx * 4 + j];
#pragma unroll
            for (int i = 0; i < 2; ++i)
#pragma unroll
                for (int j = 0; j < 4; ++j) acc[i][j] = fmaf(a_[i], b_[j], acc[i][j]);
        }
        __syncthreads();
    }
#pragma unroll
    for (int i = 0; i < 2; ++i) {
        int gm = m0 + ty * 2 + i;
        if (gm >= NN) continue;
#pragma unroll
        for (int j = 0; j < 4; ++j) {
            int c = tx * 4 + j;
            obuf[(size_t)gm * 64 + t * 32 + c] = acc[i][j] + bpost[t * 32 + c];
        }
    }
}

__global__ __launch_bounds__(256) void pool_kernel(const float* __restrict__ h, const int* __restrict__ batch,
                                                   float* __restrict__ g) {
    int idx = blockIdx.x * 256 + threadIdx.x;
    if (idx >= NN * 64) return;
    int n = idx >> 6, f = idx & 63;
    atomicAdd(&g[batch[n] * 64 + f], h[idx]);
}

__global__ __launch_bounds__(256) void head_kernel(const float* __restrict__ gpool, const float* __restrict__ hls,
                                                   const float* __restrict__ W1, const float* __restrict__ b1,
                                                   const float* __restrict__ W2, const float* __restrict__ b2,
                                                   const float* __restrict__ W3, const float* __restrict__ b3,
                                                   float* __restrict__ out) {
    __shared__ float gin[64][96];
    __shared__ float r1[64][64];
    __shared__ float r2[64][64];
    int tid = threadIdx.x;
    for (int idx = tid; idx < 64 * 96; idx += 256) {
        int g = idx / 96, j = idx % 96;
        gin[g][j] = (j < 64) ? gpool[g * 64 + j] : hls[g * 32 + (j - 64)];
    }
    __syncthreads();
    for (int idx = tid; idx < 64 * 64; idx += 256) {
        int g = idx / 64, j = idx % 64;
        float acc = b1[j];
        for (int k = 0; k < 96; ++k) acc = fmaf(gin[g][k], W1[k * 64 + j], acc);
        r1[g][j] = fmaxf(acc, 0.f);
    }
    __syncthreads();
    for (int idx = tid; idx < 64 * 64; idx += 256) {
        int g = idx / 64, j = idx % 64;
        float acc = b2[j];
        for (int k = 0; k < 64; ++k) acc = fmaf(r1[g][k], W2[k * 64 + j], acc);
        r2[g][j] = fmaxf(acc, 0.f);
    }
    __syncthreads();
    if (tid < 64) {
        float acc = b3[0];
        for (int k = 0; k < 64; ++k) acc = fmaf(r2[tid][k], W3[k], acc);
        out[tid] = acc;
    }
}

extern "C" void kernel_launch(void* const* d_in, const int* in_sizes, int n_in,
                              void* d_out, int out_size, void* d_ws, size_t ws_size,
                              hipStream_t stream) {
    (void)in_sizes; (void)n_in; (void)out_size; (void)ws_size;
    const float* x     = (const float*)d_in[0];
    const float* eattr = (const float*)d_in[1];
    const float* hls   = (const float*)d_in[2];
    const int*   eidx  = (const int*)d_in[3];
    const int*   batch = (const int*)d_in[4];
    const float* We[2]    = {(const float*)d_in[5],  (const float*)d_in[13]};
    const float* be[2]    = {(const float*)d_in[6],  (const float*)d_in[14]};
    const float* Wpre[2]  = {(const float*)d_in[7],  (const float*)d_in[15]};
    const float* bpre[2]  = {(const float*)d_in[8],  (const float*)d_in[16]};
    const float* Wpost[2] = {(const float*)d_in[9],  (const float*)d_in[17]};
    const float* bpost[2] = {(const float*)d_in[10], (const float*)d_in[18]};
    const float* Wlin[2]  = {(const float*)d_in[11], (const float*)d_in[19]};
    const float* blin[2]  = {(const float*)d_in[12], (const float*)d_in[20]};
    const float* W1 = (const float*)d_in[21]; const float* b1 = (const float*)d_in[22];
    const float* W2 = (const float*)d_in[23]; const float* b2 = (const float*)d_in[24];
    const float* W3 = (const float*)d_in[25]; const float* b3 = (const float*)d_in[26];
    float* out = (float*)d_out;

    char* ws = (char*)d_ws;
    size_t off = 0;
    auto carve = [&](size_t bytes) -> char* {
        char* p = ws + off;
        off = (off + bytes + 255) & ~(size_t)255;
        return p;
    };
    int*    cnt     = (int*)carve((size_t)NN * 4);
    int*    csr_src = (int*)carve((size_t)NN * CAP * 4);
    float2* csr_ea  = (float2*)carve((size_t)NN * CAP * 8);
    float*  AB      = (float*)carve((size_t)NN * 256 * 4);
    float*  agg     = (float*)carve((size_t)NN * 512 * 4);
    float2* sc      = (float2*)carve((size_t)NN * 8);
    float*  obuf    = (float*)carve((size_t)NN * 64 * 4);
    float*  h1      = (float*)carve((size_t)NN * 64 * 4);
    float*  U       = (float*)carve(256 * 4);
    float*  Wab     = (float*)carve(16384 * 4);
    float*  bias_ab = (float*)carve(256 * 4);
    float*  pool    = (float*)carve(64 * 64 * 4);
    float*  h2      = AB;  // AB dead after layer-1 aggregate

    const int MB = (NN + 63) / 64;

    zero_kernel<<<(NN + 255) / 256, 256, 0, stream>>>(cnt, NN);
    zero_kernel<<<(64 * 64 + 255) / 256, 256, 0, stream>>>((int*)pool, 64 * 64);
    build_csr<<<(EE + 255) / 256, 256, 0, stream>>>(eidx, eattr, cnt, csr_src, csr_ea);

    // layer 0 (F=32)
    prep_weights<32><<<1, 256, 0, stream>>>(We[0], be[0], Wpre[0], bpre[0], U, Wab, bias_ab);
    gemm_tiled<false><<<dim3(MB, 2), 256, 0, stream>>>(x, Wab, bias_ab, AB, NN, 32, 128);
    aggregate<32><<<(NN + 3) / 4, 256, 0, stream>>>(AB, cnt, csr_src, csr_ea, U, agg, sc);
    post_gemm<32><<<dim3(MB, 2), 256, 0, stream>>>(x, agg, sc, Wpost[0], bpost[0], obuf);
    gemm_tiled<true><<<dim3(MB, 1), 256, 0, stream>>>(obuf, Wlin[0], blin[0], h1, NN, 64, 64);

    // layer 1 (F=64)
    prep_weights<64><<<1, 256, 0, stream>>>(We[1], be[1], Wpre[1], bpre[1], U, Wab, bias_ab);
    gemm_tiled<false><<<dim3(MB, 4), 256, 0, stream>>>(h1, Wab, bias_ab, AB, NN, 64, 256);
    aggregate<64><<<(NN + 3) / 4, 256, 0, stream>>>(AB, cnt, csr_src, csr_ea, U, agg, sc);
    post_gemm<64><<<dim3(MB, 2), 256, 0, stream>>>(h1, agg, sc, Wpost[1], bpost[1], obuf);
    gemm_tiled<true><<<dim3(MB, 1), 256, 0, stream>>>(obuf, Wlin[1], blin[1], h2, NN, 64, 64);

    // pooling + head
    pool_kernel<<<(NN * 64 + 255) / 256, 256, 0, stream>>>(h2, batch, pool);
    head_kernel<<<1, 256, 0, stream>>>(pool, hls, W1, b1, W2, b2, W3, b3, out);
}

// Round 2
// 633.620 us; speedup vs baseline: 1.5212x; 1.5212x over previous
//
#include <hip/hip_runtime.h>
#include <math.h>
#include <float.h>

// Problem constants (HierNet_55705725829422)
#define NN 50000      // nodes
#define EE 800000     // edges
#define CAP 64        // max in-degree capacity (Poisson(16): P(>=64) ~ 1e-19)

__device__ __constant__ float kAVG_LOG = 2.8332133440562162f; // log(17)

__global__ __launch_bounds__(256) void zero_kernel(int* p, int n) {
    int i = blockIdx.x * 256 + threadIdx.x;
    if (i < n) p[i] = 0;
}

__global__ __launch_bounds__(256) void build_csr(const int* __restrict__ ei, const float* __restrict__ ea,
                                                 int* __restrict__ cnt, int* __restrict__ csr_src,
                                                 float2* __restrict__ csr_ea) {
    int e = blockIdx.x * 256 + threadIdx.x;
    if (e >= EE) return;
    int s = ei[e];
    int d = ei[EE + e];
    float2 v = *(const float2*)(ea + 2 * e);
    int p = atomicAdd(&cnt[d], 1);
    if (p < CAP) {
        csr_src[d * CAP + p] = s;
        csr_ea[d * CAP + p] = v;
    }
}

// U[c*TF+f] = sum_g We[c,g]*Wpre[t,2F+g,o]; Wab repack [F][2TF]; bias_ab (A half only)
template <int F>
__global__ __launch_bounds__(256) void prep_weights(const float* __restrict__ We, const float* __restrict__ be,
                                                    const float* __restrict__ Wpre, const float* __restrict__ bpre,
                                                    float* __restrict__ U, float* __restrict__ Wab,
                                                    float* __restrict__ bias_ab) {
    const int TF = 2 * F;
    int tid = threadIdx.x;
    for (int idx = tid; idx < 2 * TF; idx += 256) {
        int c = idx / TF, f = idx % TF;
        int t = f / F, o = f % F;
        float s = 0.f;
        for (int g = 0; g < F; ++g)
            s += We[c * F + g] * Wpre[((size_t)t * 3 * F + 2 * F + g) * F + o];
        U[idx] = s;
    }
    for (int idx = tid; idx < F * 2 * TF; idx += 256) {
        int g = idx / (2 * TF), cc = idx % (2 * TF);
        int t, o, row;
        if (cc < TF) { t = cc / F; o = cc % F; row = g; }
        else { int c2 = cc - TF; t = c2 / F; o = c2 % F; row = F + g; }
        Wab[idx] = Wpre[((size_t)t * 3 * F + row) * F + o];
    }
    for (int cc = tid; cc < 2 * TF; cc += 256) {
        float v = 0.f;
        if (cc < TF) {
            int t = cc / F, o = cc % F;
            float s = 0.f;
            for (int g = 0; g < F; ++g)
                s += be[g] * Wpre[((size_t)t * 3 * F + 2 * F + g) * F + o];
            v = s + bpre[t * F + o];
        }
        bias_ab[cc] = v;
    }
}

// Wcat[0:F][64]   = Wfold[g][j] = sum_{t,c} Wpost[t][g,c] * Wlin[t*32+c][j]
// Wcat[F:F+64][64] = Wlin
template <int F>
__global__ __launch_bounds__(256) void prep_fold(const float* __restrict__ Wpost, const float* __restrict__ Wlin,
                                                 float* __restrict__ Wcat) {
    int tid = threadIdx.x;
    for (int idx = tid; idx < F * 64; idx += 256) {
        int g = idx >> 6, j = idx & 63;
        float s = 0.f;
        for (int t = 0; t < 2; ++t)
            for (int c = 0; c < 32; ++c)
                s += Wpost[((size_t)t * 13 * F + g) * 32 + c] * Wlin[(t * 32 + c) * 64 + j];
        Wcat[idx] = s;
    }
    for (int idx = tid; idx < 64 * 64; idx += 256) Wcat[F * 64 + idx] = Wlin[idx];
}

// C[MxN] = A[MxK]@B[KxN] + bias. Tile 128x64, micro 8x4. K%32==0, N%64==0.
__global__ __launch_bounds__(256) void gemm_bias(const float* __restrict__ A, const float* __restrict__ B,
                                                 const float* __restrict__ bias, float* __restrict__ C,
                                                 int M, int K, int Ncols) {
    __shared__ float As[32][132];  // k-major, stride%32==4 -> <=4-way staging conflicts, 16B aligned
    __shared__ float Bs[32][68];
    int m0 = blockIdx.x * 128, c0 = blockIdx.y * 64;
    int tid = threadIdx.x;
    int tx = tid & 15, ty = tid >> 4;
    int ms = tid >> 3, u = tid & 7;
    float acc[8][4] = {};
    for (int k0 = 0; k0 < K; k0 += 32) {
#pragma unroll
        for (int p = 0; p < 4; ++p) {
            int m = ms + 32 * p;
            int gm = m0 + m;
            float4 v = make_float4(0.f, 0.f, 0.f, 0.f);
            if (gm < M) v = *(const float4*)(A + (size_t)gm * K + k0 + u * 4);
            As[u * 4 + 0][m] = v.x; As[u * 4 + 1][m] = v.y;
            As[u * 4 + 2][m] = v.z; As[u * 4 + 3][m] = v.w;
        }
#pragma unroll
        for (int p = 0; p < 2; ++p) {
            int idx = tid + 256 * p;
            int kk = idx >> 4, q = idx & 15;
            *(float4*)&Bs[kk][q * 4] = *(const float4*)(B + (size_t)(k0 + kk) * Ncols + c0 + q * 4);
        }
        __syncthreads();
#pragma unroll 8
        for (int k = 0; k < 32; ++k) {
            float a0[8], b0[4];
            *(float4*)&a0[0] = *(const float4*)&As[k][ty * 8];
            *(float4*)&a0[4] = *(const float4*)&As[k][ty * 8 + 4];
            *(float4*)&b0[0] = *(const float4*)&Bs[k][tx * 4];
#pragma unroll
            for (int i = 0; i < 8; ++i)
#pragma unroll
                for (int j = 0; j < 4; ++j) acc[i][j] = fmaf(a0[i], b0[j], acc[i][j]);
        }
        __syncthreads();
    }
    float bj[4];
#pragma unroll
    for (int j = 0; j < 4; ++j) bj[j] = bias[c0 + tx * 4 + j];
#pragma unroll
    for (int i = 0; i < 8; ++i) {
        int gm = m0 + ty * 8 + i;
        if (gm >= M) continue;
        float4 v = make_float4(acc[i][0] + bj[0], acc[i][1] + bj[1], acc[i][2] + bj[2], acc[i][3] + bj[3]);
        *(float4*)(C + (size_t)gm * Ncols + c0 + tx * 4) = v;
    }
}

// one wave per node: m = base + B[src] + ea.x*U0 + ea.y*U1; mean/min/max/std -> agg[N][T][4F]
template <int F>
__global__ __launch_bounds__(256) void aggregate(const float* __restrict__ AB, const int* __restrict__ cnt,
                                                 const int* __restrict__ csr_src, const float2* __restrict__ csr_ea,
                                                 const float* __restrict__ U, float* __restrict__ agg,
                                                 float2* __restrict__ sc) {
    const int TF = 2 * F;
    const int FPL = TF / 64;
    int wave = threadIdx.x >> 6, lane = threadIdx.x & 63;
    int n = blockIdx.x * 4 + wave;
    if (n >= NN) return;

    float base[FPL], u0[FPL], u1[FPL], sum[FPL], sq[FPL], mn[FPL], mx[FPL];
#pragma unroll
    for (int r = 0; r < FPL; ++r) {
        int f = lane + 64 * r;
        base[r] = AB[(size_t)n * (2 * TF) + f];
        u0[r] = U[f];
        u1[r] = U[TF + f];
        sum[r] = 0.f; sq[r] = 0.f; mn[r] = FLT_MAX; mx[r] = -FLT_MAX;
    }
    int deg = cnt[n];
    int ec = deg < CAP ? deg : CAP;
    const int ebase = n * CAP;
    for (int e = 0; e < ec; ++e) {
        int s = csr_src[ebase + e];
        float2 ea = csr_ea[ebase + e];
        const float* Brow = AB + (size_t)s * (2 * TF) + TF;
#pragma unroll
        for (int r = 0; r < FPL; ++r) {
            int f = lane + 64 * r;
            float m = base[r] + Brow[f] + ea.x * u0[r] + ea.y * u1[r];
            sum[r] += m;
            sq[r] = fmaf(m, m, sq[r]);
            mn[r] = fminf(mn[r], m);
            mx[r] = fmaxf(mx[r], m);
        }
    }
    float d = (float)(deg > 1 ? deg : 1);
    float inv_d = 1.f / d;
#pragma unroll
    for (int r = 0; r < FPL; ++r) {
        int f = lane + 64 * r;
        float mean = sum[r] * inv_d;
        float msq = sq[r] * inv_d;
        float var = msq - mean * mean;
        float stdv = sqrtf(fmaxf(var, 0.f) + 1e-5f);
        float vmn = deg > 0 ? mn[r] : 0.f;
        float vmx = deg > 0 ? mx[r] : 0.f;
        int t = f / F, o = f % F;
        size_t rowb = (size_t)n * (4 * TF) + (size_t)t * (4 * F);
        agg[rowb + o] = mean;
        agg[rowb + F + o] = vmn;
        agg[rowb + 2 * F + o] = vmx;
        agg[rowb + 3 * F + o] = stdv;
    }
    if (lane == 0) {
        float logd = logf(d + 1.f);
        sc[n] = make_float2(logd / kAVG_LOG, kAVG_LOG / logd);
    }
}

// Z_b = agg_t @ Wpost_t[b-block]; P[n][t*32+c] = Z0 + s1*Z1 + s2*Z2 + bpost (combine in registers)
// Tile 64 rows x 96 cols (3 b-blocks x 32), micro 8 rows x 3 cols. grid(ceil(N/64), T)
template <int F>
__global__ __launch_bounds__(256) void gemm_z(const float* __restrict__ agg, const float* __restrict__ Wpost,
                                              const float* __restrict__ bpost, const float2* __restrict__ sc,
                                              float* __restrict__ P) {
    const int K = 4 * F;
    const int RS = 8 * F;  // agg row stride
    __shared__ float As[32][68];
    __shared__ float Bs[32][100];
    int m0 = blockIdx.x * 64;
    int t = blockIdx.y;
    int tid = threadIdx.x;
    int tx = tid & 31, ty = tid >> 5;
    int ms = tid >> 3, u = tid & 7;
    const float* Wb = Wpost + ((size_t)t * 13 * F + F) * 32;  // [12F][32]
    float acc[8][3] = {};
    for (int k0 = 0; k0 < K; k0 += 32) {
#pragma unroll
        for (int p = 0; p < 2; ++p) {
            int m = ms + 32 * p;
            int gm = m0 + m;
            float4 v = make_float4(0.f, 0.f, 0.f, 0.f);
            if (gm < NN) v = *(const float4*)(agg + (size_t)gm * RS + t * 4 * F + k0 + u * 4);
            As[u * 4 + 0][m] = v.x; As[u * 4 + 1][m] = v.y;
            As[u * 4 + 2][m] = v.z; As[u * 4 + 3][m] = v.w;
        }
#pragma unroll
        for (int p = 0; p < 3; ++p) {
            int idx = tid + 256 * p;          // 0..767 quads
            int kk = idx / 24, q = idx % 24;  // q = b*8 + cq
            int b = q >> 3, cq = q & 7;
            *(float4*)&Bs[kk][b * 32 + cq * 4] =
                *(const float4*)(Wb + ((size_t)(b * 4 * F + k0 + kk)) * 32 + cq * 4);
        }
        __syncthreads();
#pragma unroll 8
        for (int k = 0; k < 32; ++k) {
            float a0[8];
            *(float4*)&a0[0] = *(const float4*)&As[k][ty * 8];
            *(float4*)&a0[4] = *(const float4*)&As[k][ty * 8 + 4];
            float b0 = Bs[k][tx], b1 = Bs[k][32 + tx], b2 = Bs[k][64 + tx];
#pragma unroll
            for (int i = 0; i < 8; ++i) {
                acc[i][0] = fmaf(a0[i], b0, acc[i][0]);
                acc[i][1] = fmaf(a0[i], b1, acc[i][1]);
                acc[i][2] = fmaf(a0[i], b2, acc[i][2]);
            }
        }
        __syncthreads();
    }
    float bp = bpost[t * 32 + tx];
#pragma unroll
    for (int i = 0; i < 8; ++i) {
        int gm = m0 + ty * 8 + i;
        if (gm >= NN) continue;
        float2 s = sc[gm];
        P[(size_t)gm * 64 + t * 32 + tx] = acc[i][0] + s.x * acc[i][1] + s.y * acc[i][2] + bp;
    }
}

// H = relu([x | P] @ Wcat + blin). K = FIN+64, N=64. Tile 128x64, micro 8x4.
template <int FIN>
__global__ __launch_bounds__(256) void gemm_final(const float* __restrict__ x, const float* __restrict__ P,
                                                  const float* __restrict__ Wcat, const float* __restrict__ blin,
                                                  float* __restrict__ H) {
    const int K = FIN + 64;
    __shared__ float As[32][132];
    __shared__ float Bs[32][68];
    int m0 = blockIdx.x * 128;
    int tid = threadIdx.x;
    int tx = tid & 15, ty = tid >> 4;
    int ms = tid >> 3, u = tid & 7;
    float acc[8][4] = {};
    for (int k0 = 0; k0 < K; k0 += 32) {
        const float* Asrc; int rs, koff;
        if (k0 < FIN) { Asrc = x; rs = FIN; koff = k0; }
        else { Asrc = P; rs = 64; koff = k0 - FIN; }
#pragma unroll
        for (int p = 0; p < 4; ++p) {
            int m = ms + 32 * p;
            int gm = m0 + m;
            float4 v = make_float4(0.f, 0.f, 0.f, 0.f);
            if (gm < NN) v = *(const float4*)(Asrc + (size_t)gm * rs + koff + u * 4);
            As[u * 4 + 0][m] = v.x; As[u * 4 + 1][m] = v.y;
            As[u * 4 + 2][m] = v.z; As[u * 4 + 3][m] = v.w;
        }
#pragma unroll
        for (int p = 0; p < 2; ++p) {
            int idx = tid + 256 * p;
            int kk = idx >> 4, q = idx & 15;
            *(float4*)&Bs[kk][q * 4] = *(const float4*)(Wcat + (size_t)(k0 + kk) * 64 + q * 4);
        }
        __syncthreads();
#pragma unroll 8
        for (int k = 0; k < 32; ++k) {
            float a0[8], b0[4];
            *(float4*)&a0[0] = *(const float4*)&As[k][ty * 8];
            *(float4*)&a0[4] = *(const float4*)&As[k][ty * 8 + 4];
            *(float4*)&b0[0] = *(const float4*)&Bs[k][tx * 4];
#pragma unroll
            for (int i = 0; i < 8; ++i)
#pragma unroll
                for (int j = 0; j < 4; ++j) acc[i][j] = fmaf(a0[i], b0[j], acc[i][j]);
        }
        __syncthreads();
    }
    float bj[4];
#pragma unroll
    for (int j = 0; j < 4; ++j) bj[j] = blin[tx * 4 + j];
#pragma unroll
    for (int i = 0; i < 8; ++i) {
        int gm = m0 + ty * 8 + i;
        if (gm >= NN) continue;
        float4 v = make_float4(fmaxf(acc[i][0] + bj[0], 0.f), fmaxf(acc[i][1] + bj[1], 0.f),
                               fmaxf(acc[i][2] + bj[2], 0.f), fmaxf(acc[i][3] + bj[3], 0.f));
        *(float4*)(H + (size_t)gm * 64 + tx * 4) = v;
    }
}

// pool: run-length register accumulation over sorted batch, flush atomics on segment change
__global__ __launch_bounds__(256) void pool_kernel(const float* __restrict__ h, const int* __restrict__ batch,
                                                   float* __restrict__ g) {
    int f = threadIdx.x & 63;
    int w = threadIdx.x >> 6;
    int n0 = blockIdx.x * 64 + w * 16;
    float acc = 0.f; int cur = -1;
    for (int i = 0; i < 16; ++i) {
        int n = n0 + i;
        if (n >= NN) break;
        int b = batch[n];
        if (b != cur) {
            if (cur >= 0) atomicAdd(&g[cur * 64 + f], acc);
            cur = b; acc = 0.f;
        }
        acc += h[(size_t)n * 64 + f];
    }
    if (cur >= 0) atomicAdd(&g[cur * 64 + f], acc);
}

__global__ __launch_bounds__(256) void head_kernel(const float* __restrict__ gpool, const float* __restrict__ hls,
                                                   const float* __restrict__ W1, const float* __restrict__ b1,
                                                   const float* __restrict__ W2, const float* __restrict__ b2,
                                                   const float* __restrict__ W3, const float* __restrict__ b3,
                                                   float* __restrict__ out) {
    __shared__ float gin[64][96];
    __shared__ float r1[64][64];
    __shared__ float r2[64][64];
    int tid = threadIdx.x;
    for (int idx = tid; idx < 64 * 96; idx += 256) {
        int g = idx / 96, j = idx % 96;
        gin[g][j] = (j < 64) ? gpool[g * 64 + j] : hls[g * 32 + (j - 64)];
    }
    __syncthreads();
    for (int idx = tid; idx < 64 * 64; idx += 256) {
        int g = idx / 64, j = idx % 64;
        float acc = b1[j];
        for (int k = 0; k < 96; ++k) acc = fmaf(gin[g][k], W1[k * 64 + j], acc);
        r1[g][j] = fmaxf(acc, 0.f);
    }
    __syncthreads();
    for (int idx = tid; idx < 64 * 64; idx += 256) {
        int g = idx / 64, j = idx % 64;
        float acc = b2[j];
        for (int k = 0; k < 64; ++k) acc = fmaf(r1[g][k], W2[k * 64 + j], acc);
        r2[g][j] = fmaxf(acc, 0.f);
    }
    __syncthreads();
    if (tid < 64) {
        float acc = b3[0];
        for (int k = 0; k < 64; ++k) acc = fmaf(r2[tid][k], W3[k], acc);
        out[tid] = acc;
    }
}

extern "C" void kernel_launch(void* const* d_in, const int* in_sizes, int n_in,
                              void* d_out, int out_size, void* d_ws, size_t ws_size,
                              hipStream_t stream) {
    (void)in_sizes; (void)n_in; (void)out_size; (void)ws_size;
    const float* x     = (const float*)d_in[0];
    const float* eattr = (const float*)d_in[1];
    const float* hls   = (const float*)d_in[2];
    const int*   eidx  = (const int*)d_in[3];
    const int*   batch = (const int*)d_in[4];
    const float* We[2]    = {(const float*)d_in[5],  (const float*)d_in[13]};
    const float* be[2]    = {(const float*)d_in[6],  (const float*)d_in[14]};
    const float* Wpre[2]  = {(const float*)d_in[7],  (const float*)d_in[15]};
    const float* bpre[2]  = {(const float*)d_in[8],  (const float*)d_in[16]};
    const float* Wpost[2] = {(const float*)d_in[9],  (const float*)d_in[17]};
    const float* bpost[2] = {(const float*)d_in[10], (const float*)d_in[18]};
    const float* Wlin[2]  = {(const float*)d_in[11], (const float*)d_in[19]};
    const float* blin[2]  = {(const float*)d_in[12], (const float*)d_in[20]};
    const float* W1 = (const float*)d_in[21]; const float* b1 = (const float*)d_in[22];
    const float* W2 = (const float*)d_in[23]; const float* b2 = (const float*)d_in[24];
    const float* W3 = (const float*)d_in[25]; const float* b3 = (const float*)d_in[26];
    float* out = (float*)d_out;

    char* ws = (char*)d_ws;
    size_t off = 0;
    auto carve = [&](size_t bytes) -> char* {
        char* p = ws + off;
        off = (off + bytes + 255) & ~(size_t)255;
        return p;
    };
    int*    cnt     = (int*)carve((size_t)NN * 4);
    int*    csr_src = (int*)carve((size_t)NN * CAP * 4);
    float2* csr_ea  = (float2*)carve((size_t)NN * CAP * 8);
    float*  AB      = (float*)carve((size_t)NN * 256 * 4);
    float*  agg     = (float*)carve((size_t)NN * 512 * 4);
    float2* sc      = (float2*)carve((size_t)NN * 8);
    float*  P       = (float*)carve((size_t)NN * 64 * 4);
    float*  h1      = (float*)carve((size_t)NN * 64 * 4);
    float*  U       = (float*)carve(256 * 4);
    float*  Wab     = (float*)carve(16384 * 4);
    float*  bias_ab = (float*)carve(256 * 4);
    float*  Wcat    = (float*)carve(128 * 64 * 4);
    float*  pool    = (float*)carve(64 * 64 * 4);
    float*  h2      = AB;  // AB dead after layer-1 aggregate

    const int MB128 = (NN + 127) / 128;  // 391
    const int MB64  = (NN + 63) / 64;    // 782

    zero_kernel<<<(NN + 255) / 256, 256, 0, stream>>>(cnt, NN);
    zero_kernel<<<(64 * 64 + 255) / 256, 256, 0, stream>>>((int*)pool, 64 * 64);
    build_csr<<<(EE + 255) / 256, 256, 0, stream>>>(eidx, eattr, cnt, csr_src, csr_ea);

    // ---------------- layer 0 (F=32) ----------------
    prep_weights<32><<<1, 256, 0, stream>>>(We[0], be[0], Wpre[0], bpre[0], U, Wab, bias_ab);
    prep_fold<32><<<1, 256, 0, stream>>>(Wpost[0], Wlin[0], Wcat);
    gemm_bias<<<dim3(MB128, 2), 256, 0, stream>>>(x, Wab, bias_ab, AB, NN, 32, 128);
    aggregate<32><<<(NN + 3) / 4, 256, 0, stream>>>(AB, cnt, csr_src, csr_ea, U, agg, sc);
    gemm_z<32><<<dim3(MB64, 2), 256, 0, stream>>>(agg, Wpost[0], bpost[0], sc, P);
    gemm_final<32><<<dim3(MB128, 1), 256, 0, stream>>>(x, P, Wcat, blin[0], h1);

    // ---------------- layer 1 (F=64) ----------------
    prep_weights<64><<<1, 256, 0, stream>>>(We[1], be[1], Wpre[1], bpre[1], U, Wab, bias_ab);
    prep_fold<64><<<1, 256, 0, stream>>>(Wpost[1], Wlin[1], Wcat);
    gemm_bias<<<dim3(MB128, 4), 256, 0, stream>>>(h1, Wab, bias_ab, AB, NN, 64, 256);
    aggregate<64><<<(NN + 3) / 4, 256, 0, stream>>>(AB, cnt, csr_src, csr_ea, U, agg, sc);
    gemm_z<64><<<dim3(MB64, 2), 256, 0, stream>>>(agg, Wpost[1], bpost[1], sc, P);
    gemm_final<64><<<dim3(MB128, 1), 256, 0, stream>>>(h1, P, Wcat, blin[1], h2);

    // ---------------- pooling + head ----------------
    pool_kernel<<<MB64, 256, 0, stream>>>(h2, batch, pool);
    head_kernel<<<1, 256, 0, stream>>>(pool, hls, W1, b1, W2, b2, W3, b3, out);
}

// Round 3
// 580.526 us; speedup vs baseline: 1.6604x; 1.0915x over previous
//
#include <hip/hip_runtime.h>
#include <math.h>
#include <float.h>

// Problem constants (HierNet_55705725829422)
#define NN 50000      // nodes
#define EE 800000     // edges
#define CAP 64        // max in-degree capacity (Poisson(16): P(>=64) ~ 1e-19)

__device__ __constant__ float kAVG_LOG = 2.8332133440562162f; // log(17)

__global__ __launch_bounds__(256) void zero_init(int* cnt, float* pool) {
    int i = blockIdx.x * 256 + threadIdx.x;
    if (i < NN) cnt[i] = 0;
    if (i < 64 * 64) pool[i] = 0.f;
}

__global__ __launch_bounds__(256) void build_csr(const int* __restrict__ ei, const float* __restrict__ ea,
                                                 int* __restrict__ cnt, int* __restrict__ csr_src,
                                                 float2* __restrict__ csr_ea) {
    int e = blockIdx.x * 256 + threadIdx.x;
    if (e >= EE) return;
    int s = ei[e];
    int d = ei[EE + e];
    float2 v = *(const float2*)(ea + 2 * e);
    int p = atomicAdd(&cnt[d], 1);
    if (p < CAP) {
        csr_src[d * CAP + p] = s;
        csr_ea[d * CAP + p] = v;
    }
}

// fused per-layer weight prep:
//  U[c*TF+f] = sum_g We[c,g]*Wpre[t,2F+g,o]           (f = t*F+o)
//  Wab[g][cc] repack of Wpre dst/src halves           ([F][2TF])
//  bias_ab    = be@Wpre_enc + bpre on A half, 0 on B half
//  Wcat[0:F]  = Wfold = Wpost_xblock @ Wlin ; Wcat[F:F+64] = Wlin
template <int F>
__global__ __launch_bounds__(256) void prep_layer(const float* __restrict__ We, const float* __restrict__ be,
                                                  const float* __restrict__ Wpre, const float* __restrict__ bpre,
                                                  const float* __restrict__ Wpost, const float* __restrict__ Wlin,
                                                  float* __restrict__ U, float* __restrict__ Wab,
                                                  float* __restrict__ bias_ab, float* __restrict__ Wcat) {
    const int TF = 2 * F;
    int tid = threadIdx.x;
    for (int idx = tid; idx < 2 * TF; idx += 256) {
        int c = idx / TF, f = idx % TF;
        int t = f / F, o = f % F;
        float s = 0.f;
        for (int g = 0; g < F; ++g)
            s += We[c * F + g] * Wpre[((size_t)t * 3 * F + 2 * F + g) * F + o];
        U[idx] = s;
    }
    for (int idx = tid; idx < F * 2 * TF; idx += 256) {
        int g = idx / (2 * TF), cc = idx % (2 * TF);
        int t, o, row;
        if (cc < TF) { t = cc / F; o = cc % F; row = g; }
        else { int c2 = cc - TF; t = c2 / F; o = c2 % F; row = F + g; }
        Wab[idx] = Wpre[((size_t)t * 3 * F + row) * F + o];
    }
    for (int cc = tid; cc < 2 * TF; cc += 256) {
        float v = 0.f;
        if (cc < TF) {
            int t = cc / F, o = cc % F;
            float s = 0.f;
            for (int g = 0; g < F; ++g)
                s += be[g] * Wpre[((size_t)t * 3 * F + 2 * F + g) * F + o];
            v = s + bpre[t * F + o];
        }
        bias_ab[cc] = v;
    }
    for (int idx = tid; idx < F * 64; idx += 256) {
        int g = idx >> 6, j = idx & 63;
        float s = 0.f;
        for (int t = 0; t < 2; ++t)
            for (int c = 0; c < 32; ++c)
                s += Wpost[((size_t)t * 13 * F + g) * 32 + c] * Wlin[(t * 32 + c) * 64 + j];
        Wcat[idx] = s;
    }
    for (int idx = tid; idx < 64 * 64; idx += 256) Wcat[F * 64 + idx] = Wlin[idx];
}

// C[MxN] = A[MxK]@B[KxN] + bias. Tile 128x64, micro 8x4. K%32==0, N%64==0.
__global__ __launch_bounds__(256) void gemm_bias(const float* __restrict__ A, const float* __restrict__ B,
                                                 const float* __restrict__ bias, float* __restrict__ C,
                                                 int M, int K, int Ncols) {
    __shared__ float As[32][132];
    __shared__ float Bs[32][68];
    int m0 = blockIdx.x * 128, c0 = blockIdx.y * 64;
    int tid = threadIdx.x;
    int tx = tid & 15, ty = tid >> 4;
    int ms = tid >> 3, u = tid & 7;
    float acc[8][4] = {};
    for (int k0 = 0; k0 < K; k0 += 32) {
#pragma unroll
        for (int p = 0; p < 4; ++p) {
            int m = ms + 32 * p;
            int gm = m0 + m;
            float4 v = make_float4(0.f, 0.f, 0.f, 0.f);
            if (gm < M) v = *(const float4*)(A + (size_t)gm * K + k0 + u * 4);
            As[u * 4 + 0][m] = v.x; As[u * 4 + 1][m] = v.y;
            As[u * 4 + 2][m] = v.z; As[u * 4 + 3][m] = v.w;
        }
#pragma unroll
        for (int p = 0; p < 2; ++p) {
            int idx = tid + 256 * p;
            int kk = idx >> 4, q = idx & 15;
            *(float4*)&Bs[kk][q * 4] = *(const float4*)(B + (size_t)(k0 + kk) * Ncols + c0 + q * 4);
        }
        __syncthreads();
#pragma unroll 8
        for (int k = 0; k < 32; ++k) {
            float a0[8], b0[4];
            *(float4*)&a0[0] = *(const float4*)&As[k][ty * 8];
            *(float4*)&a0[4] = *(const float4*)&As[k][ty * 8 + 4];
            *(float4*)&b0[0] = *(const float4*)&Bs[k][tx * 4];
#pragma unroll
            for (int i = 0; i < 8; ++i)
#pragma unroll
                for (int j = 0; j < 4; ++j) acc[i][j] = fmaf(a0[i], b0[j], acc[i][j]);
        }
        __syncthreads();
    }
    float bj[4];
#pragma unroll
    for (int j = 0; j < 4; ++j) bj[j] = bias[c0 + tx * 4 + j];
#pragma unroll
    for (int i = 0; i < 8; ++i) {
        int gm = m0 + ty * 8 + i;
        if (gm >= M) continue;
        float4 v = make_float4(acc[i][0] + bj[0], acc[i][1] + bj[1], acc[i][2] + bj[2], acc[i][3] + bj[3]);
        *(float4*)(C + (size_t)gm * Ncols + c0 + tx * 4) = v;
    }
}

// aggregate: one wave per (node, 64-feature half). CSR entries preloaded lane-parallel,
// broadcast via shfl; gathers issued in batches of 8 independent loads.
// q = B[src][f] + ea.x*u0 + ea.y*u1 (base pulled out: std shift-invariant).
template <int F>
__global__ __launch_bounds__(256) void aggregate(const float* __restrict__ AB, const int* __restrict__ cnt,
                                                 const int* __restrict__ csr_src, const float2* __restrict__ csr_ea,
                                                 const float* __restrict__ U, float* __restrict__ agg,
                                                 float2* __restrict__ sc) {
    const int TF = 2 * F;
    const int SPN = TF / 64;  // slots (waves) per node
    int lane = threadIdx.x & 63;
    int slot = blockIdx.x * 4 + (threadIdx.x >> 6);
    int n = slot / SPN;
    int half = slot - n * SPN;
    if (n >= NN) return;
    int f = half * 64 + lane;

    float base = AB[(size_t)n * (2 * TF) + f];
    float u0 = U[f], u1 = U[TF + f];
    int deg = cnt[n];
    int ec = deg < CAP ? deg : CAP;

    float sum = 0.f, sq = 0.f, mn = FLT_MAX, mx = -FLT_MAX;
    if (ec > 0) {
        int ebase = n * CAP;
        int myi = lane < ec ? lane : ec - 1;
        int msrc = csr_src[ebase + myi];
        float2 mea = csr_ea[ebase + myi];
        const float* Bcol = AB + TF + f;  // + s*2TF per row
        for (int e = 0; e < ec; e += 8) {
            int sb[8]; float ex[8], ey[8], v[8];
#pragma unroll
            for (int i = 0; i < 8; ++i) {
                sb[i] = __shfl(msrc, e + i);
                ex[i] = __shfl(mea.x, e + i);
                ey[i] = __shfl(mea.y, e + i);
            }
#pragma unroll
            for (int i = 0; i < 8; ++i)
                if (e + i < ec) v[i] = Bcol[(size_t)sb[i] * (2 * TF)];
#pragma unroll
            for (int i = 0; i < 8; ++i) {
                if (e + i < ec) {
                    float q = fmaf(ex[i], u0, fmaf(ey[i], u1, v[i]));
                    sum += q;
                    sq = fmaf(q, q, sq);
                    mn = fminf(mn, q);
                    mx = fmaxf(mx, q);
                }
            }
        }
    }
    float d = (float)(deg > 1 ? deg : 1);
    float inv_d = 1.f / d;
    float mean_q = sum * inv_d;
    float var = sq * inv_d - mean_q * mean_q;
    float stdv = sqrtf(fmaxf(var, 0.f) + 1e-5f);
    bool has = deg > 0;
    float mean = has ? base + mean_q : 0.f;  // ref: s/d = 0 when no edges
    float vmn = has ? base + mn : 0.f;
    float vmx = has ? base + mx : 0.f;
    int t = f / F, o = f - t * F;
    size_t rowb = (size_t)n * (4 * TF) + (size_t)t * (4 * F);
    agg[rowb + o] = mean;
    agg[rowb + F + o] = vmn;
    agg[rowb + 2 * F + o] = vmx;
    agg[rowb + 3 * F + o] = stdv;
    if (half == 0 && lane == 0) {
        float logd = logf(d + 1.f);
        sc[n] = make_float2(logd / kAVG_LOG, kAVG_LOG / logd);
    }
}

// Z_b = agg_t @ Wpost_t[b]; P[n][t*32+c] = Z0 + s1*Z1 + s2*Z2 + bpost (registers combine)
template <int F>
__global__ __launch_bounds__(256) void gemm_z(const float* __restrict__ agg, const float* __restrict__ Wpost,
                                              const float* __restrict__ bpost, const float2* __restrict__ sc,
                                              float* __restrict__ P) {
    const int K = 4 * F;
    const int RS = 8 * F;
    __shared__ float As[32][68];
    __shared__ float Bs[32][100];
    int m0 = blockIdx.x * 64;
    int t = blockIdx.y;
    int tid = threadIdx.x;
    int tx = tid & 31, ty = tid >> 5;
    int ms = tid >> 3, u = tid & 7;
    const float* Wb = Wpost + ((size_t)t * 13 * F + F) * 32;
    float acc[8][3] = {};
    for (int k0 = 0; k0 < K; k0 += 32) {
#pragma unroll
        for (int p = 0; p < 2; ++p) {
            int m = ms + 32 * p;
            int gm = m0 + m;
            float4 v = make_float4(0.f, 0.f, 0.f, 0.f);
            if (gm < NN) v = *(const float4*)(agg + (size_t)gm * RS + t * 4 * F + k0 + u * 4);
            As[u * 4 + 0][m] = v.x; As[u * 4 + 1][m] = v.y;
            As[u * 4 + 2][m] = v.z; As[u * 4 + 3][m] = v.w;
        }
#pragma unroll
        for (int p = 0; p < 3; ++p) {
            int idx = tid + 256 * p;
            int kk = idx / 24, q = idx % 24;
            int b = q >> 3, cq = q & 7;
            *(float4*)&Bs[kk][b * 32 + cq * 4] =
                *(const float4*)(Wb + ((size_t)(b * 4 * F + k0 + kk)) * 32 + cq * 4);
        }
        __syncthreads();
#pragma unroll 8
        for (int k = 0; k < 32; ++k) {
            float a0[8];
            *(float4*)&a0[0] = *(const float4*)&As[k][ty * 8];
            *(float4*)&a0[4] = *(const float4*)&As[k][ty * 8 + 4];
            float b0 = Bs[k][tx], b1 = Bs[k][32 + tx], b2 = Bs[k][64 + tx];
#pragma unroll
            for (int i = 0; i < 8; ++i) {
                acc[i][0] = fmaf(a0[i], b0, acc[i][0]);
                acc[i][1] = fmaf(a0[i], b1, acc[i][1]);
                acc[i][2] = fmaf(a0[i], b2, acc[i][2]);
            }
        }
        __syncthreads();
    }
    float bp = bpost[t * 32 + tx];
#pragma unroll
    for (int i = 0; i < 8; ++i) {
        int gm = m0 + ty * 8 + i;
        if (gm >= NN) continue;
        float2 s = sc[gm];
        P[(size_t)gm * 64 + t * 32 + tx] = acc[i][0] + s.x * acc[i][1] + s.y * acc[i][2] + bp;
    }
}

// H = relu([x | P] @ Wcat + blin). If POOL: atomic-add rows into pool[batch] instead of storing H.
template <int FIN, bool POOL>
__global__ __launch_bounds__(256) void gemm_final(const float* __restrict__ x, const float* __restrict__ P,
                                                  const float* __restrict__ Wcat, const float* __restrict__ blin,
                                                  float* __restrict__ H, const int* __restrict__ batch,
                                                  float* __restrict__ pool) {
    const int K = FIN + 64;
    __shared__ float As[32][132];
    __shared__ float Bs[32][68];
    int m0 = blockIdx.x * 128;
    int tid = threadIdx.x;
    int tx = tid & 15, ty = tid >> 4;
    int ms = tid >> 3, u = tid & 7;
    float acc[8][4] = {};
    for (int k0 = 0; k0 < K; k0 += 32) {
        const float* Asrc; int rs, koff;
        if (k0 < FIN) { Asrc = x; rs = FIN; koff = k0; }
        else { Asrc = P; rs = 64; koff = k0 - FIN; }
#pragma unroll
        for (int p = 0; p < 4; ++p) {
            int m = ms + 32 * p;
            int gm = m0 + m;
            float4 v = make_float4(0.f, 0.f, 0.f, 0.f);
            if (gm < NN) v = *(const float4*)(Asrc + (size_t)gm * rs + koff + u * 4);
            As[u * 4 + 0][m] = v.x; As[u * 4 + 1][m] = v.y;
            As[u * 4 + 2][m] = v.z; As[u * 4 + 3][m] = v.w;
        }
#pragma unroll
        for (int p = 0; p < 2; ++p) {
            int idx = tid + 256 * p;
            int kk = idx >> 4, q = idx & 15;
            *(float4*)&Bs[kk][q * 4] = *(const float4*)(Wcat + (size_t)(k0 + kk) * 64 + q * 4);
        }
        __syncthreads();
#pragma unroll 8
        for (int k = 0; k < 32; ++k) {
            float a0[8], b0[4];
            *(float4*)&a0[0] = *(const float4*)&As[k][ty * 8];
            *(float4*)&a0[4] = *(const float4*)&As[k][ty * 8 + 4];
            *(float4*)&b0[0] = *(const float4*)&Bs[k][tx * 4];
#pragma unroll
            for (int i = 0; i < 8; ++i)
#pragma unroll
                for (int j = 0; j < 4; ++j) acc[i][j] = fmaf(a0[i], b0[j], acc[i][j]);
        }
        __syncthreads();
    }
    float bj[4];
#pragma unroll
    for (int j = 0; j < 4; ++j) bj[j] = blin[tx * 4 + j];
    if (!POOL) {
#pragma unroll
        for (int i = 0; i < 8; ++i) {
            int gm = m0 + ty * 8 + i;
            if (gm >= NN) continue;
            float4 v = make_float4(fmaxf(acc[i][0] + bj[0], 0.f), fmaxf(acc[i][1] + bj[1], 0.f),
                                   fmaxf(acc[i][2] + bj[2], 0.f), fmaxf(acc[i][3] + bj[3], 0.f));
            *(float4*)(H + (size_t)gm * 64 + tx * 4) = v;
        }
    } else {
        // run-length pool over this thread's 8 consecutive rows (batch is sorted)
        float a0 = 0.f, a1 = 0.f, a2 = 0.f, a3 = 0.f;
        int cur = -1;
#pragma unroll
        for (int i = 0; i < 8; ++i) {
            int gm = m0 + ty * 8 + i;
            if (gm >= NN) continue;
            int b = batch[gm];
            if (b != cur) {
                if (cur >= 0) {
                    atomicAdd(&pool[cur * 64 + tx * 4 + 0], a0);
                    atomicAdd(&pool[cur * 64 + tx * 4 + 1], a1);
                    atomicAdd(&pool[cur * 64 + tx * 4 + 2], a2);
                    atomicAdd(&pool[cur * 64 + tx * 4 + 3], a3);
                }
                cur = b; a0 = a1 = a2 = a3 = 0.f;
            }
            a0 += fmaxf(acc[i][0] + bj[0], 0.f);
            a1 += fmaxf(acc[i][1] + bj[1], 0.f);
            a2 += fmaxf(acc[i][2] + bj[2], 0.f);
            a3 += fmaxf(acc[i][3] + bj[3], 0.f);
        }
        if (cur >= 0) {
            atomicAdd(&pool[cur * 64 + tx * 4 + 0], a0);
            atomicAdd(&pool[cur * 64 + tx * 4 + 1], a1);
            atomicAdd(&pool[cur * 64 + tx * 4 + 2], a2);
            atomicAdd(&pool[cur * 64 + tx * 4 + 3], a3);
        }
    }
}

__global__ __launch_bounds__(256) void head_kernel(const float* __restrict__ gpool, const float* __restrict__ hls,
                                                   const float* __restrict__ W1, const float* __restrict__ b1,
                                                   const float* __restrict__ W2, const float* __restrict__ b2,
                                                   const float* __restrict__ W3, const float* __restrict__ b3,
                                                   float* __restrict__ out) {
    __shared__ float gin[64][96];
    __shared__ float r1[64][64];
    __shared__ float r2[64][64];
    int tid = threadIdx.x;
    for (int idx = tid; idx < 64 * 96; idx += 256) {
        int g = idx / 96, j = idx % 96;
        gin[g][j] = (j < 64) ? gpool[g * 64 + j] : hls[g * 32 + (j - 64)];
    }
    __syncthreads();
    for (int idx = tid; idx < 64 * 64; idx += 256) {
        int g = idx / 64, j = idx % 64;
        float acc = b1[j];
        for (int k = 0; k < 96; ++k) acc = fmaf(gin[g][k], W1[k * 64 + j], acc);
        r1[g][j] = fmaxf(acc, 0.f);
    }
    __syncthreads();
    for (int idx = tid; idx < 64 * 64; idx += 256) {
        int g = idx / 64, j = idx % 64;
        float acc = b2[j];
        for (int k = 0; k < 64; ++k) acc = fmaf(r1[g][k], W2[k * 64 + j], acc);
        r2[g][j] = fmaxf(acc, 0.f);
    }
    __syncthreads();
    if (tid < 64) {
        float acc = b3[0];
        for (int k = 0; k < 64; ++k) acc = fmaf(r2[tid][k], W3[k], acc);
        out[tid] = acc;
    }
}

extern "C" void kernel_launch(void* const* d_in, const int* in_sizes, int n_in,
                              void* d_out, int out_size, void* d_ws, size_t ws_size,
                              hipStream_t stream) {
    (void)in_sizes; (void)n_in; (void)out_size; (void)ws_size;
    const float* x     = (const float*)d_in[0];
    const float* eattr = (const float*)d_in[1];
    const float* hls   = (const float*)d_in[2];
    const int*   eidx  = (const int*)d_in[3];
    const int*   batch = (const int*)d_in[4];
    const float* We[2]    = {(const float*)d_in[5],  (const float*)d_in[13]};
    const float* be[2]    = {(const float*)d_in[6],  (const float*)d_in[14]};
    const float* Wpre[2]  = {(const float*)d_in[7],  (const float*)d_in[15]};
    const float* bpre[2]  = {(const float*)d_in[8],  (const float*)d_in[16]};
    const float* Wpost[2] = {(const float*)d_in[9],  (const float*)d_in[17]};
    const float* bpost[2] = {(const float*)d_in[10], (const float*)d_in[18]};
    const float* Wlin[2]  = {(const float*)d_in[11], (const float*)d_in[19]};
    const float* blin[2]  = {(const float*)d_in[12], (const float*)d_in[20]};
    const float* W1 = (const float*)d_in[21]; const float* b1 = (const float*)d_in[22];
    const float* W2 = (const float*)d_in[23]; const float* b2 = (const float*)d_in[24];
    const float* W3 = (const float*)d_in[25]; const float* b3 = (const float*)d_in[26];
    float* out = (float*)d_out;

    char* ws = (char*)d_ws;
    size_t off = 0;
    auto carve = [&](size_t bytes) -> char* {
        char* p = ws + off;
        off = (off + bytes + 255) & ~(size_t)255;
        return p;
    };
    int*    cnt     = (int*)carve((size_t)NN * 4);
    int*    csr_src = (int*)carve((size_t)NN * CAP * 4);
    float2* csr_ea  = (float2*)carve((size_t)NN * CAP * 8);
    float*  AB      = (float*)carve((size_t)NN * 256 * 4);
    float*  agg     = (float*)carve((size_t)NN * 512 * 4);
    float2* sc      = (float2*)carve((size_t)NN * 8);
    float*  P       = (float*)carve((size_t)NN * 64 * 4);
    float*  h1      = (float*)carve((size_t)NN * 64 * 4);
    float*  U       = (float*)carve(256 * 4);
    float*  Wab     = (float*)carve(16384 * 4);
    float*  bias_ab = (float*)carve(256 * 4);
    float*  Wcat    = (float*)carve(128 * 64 * 4);
    float*  pool    = (float*)carve(64 * 64 * 4);

    const int MB128 = (NN + 127) / 128;  // 391
    const int MB64  = (NN + 63) / 64;    // 782

    zero_init<<<(NN + 255) / 256, 256, 0, stream>>>(cnt, pool);
    build_csr<<<(EE + 255) / 256, 256, 0, stream>>>(eidx, eattr, cnt, csr_src, csr_ea);

    // ---------------- layer 0 (F=32) ----------------
    prep_layer<32><<<1, 256, 0, stream>>>(We[0], be[0], Wpre[0], bpre[0], Wpost[0], Wlin[0],
                                          U, Wab, bias_ab, Wcat);
    gemm_bias<<<dim3(MB128, 2), 256, 0, stream>>>(x, Wab, bias_ab, AB, NN, 32, 128);
    aggregate<32><<<(NN + 3) / 4, 256, 0, stream>>>(AB, cnt, csr_src, csr_ea, U, agg, sc);
    gemm_z<32><<<dim3(MB64, 2), 256, 0, stream>>>(agg, Wpost[0], bpost[0], sc, P);
    gemm_final<32, false><<<dim3(MB128, 1), 256, 0, stream>>>(x, P, Wcat, blin[0], h1, batch, pool);

    // ---------------- layer 1 (F=64) ----------------
    prep_layer<64><<<1, 256, 0, stream>>>(We[1], be[1], Wpre[1], bpre[1], Wpost[1], Wlin[1],
                                          U, Wab, bias_ab, Wcat);
    gemm_bias<<<dim3(MB128, 4), 256, 0, stream>>>(h1, Wab, bias_ab, AB, NN, 64, 256);
    aggregate<64><<<(2 * NN + 3) / 4, 256, 0, stream>>>(AB, cnt, csr_src, csr_ea, U, agg, sc);
    gemm_z<64><<<dim3(MB64, 2), 256, 0, stream>>>(agg, Wpost[1], bpost[1], sc, P);
    gemm_final<64, true><<<dim3(MB128, 1), 256, 0, stream>>>(h1, P, Wcat, blin[1], nullptr, batch, pool);

    // ---------------- head ----------------
    head_kernel<<<1, 256, 0, stream>>>(pool, hls, W1, b1, W2, b2, W3, b3, out);
}